// Round 6
// baseline (481.421 us; speedup 1.0000x reference)
//
#include <hip/hip_runtime.h>
#include <cmath>

typedef unsigned short u16;
typedef short v8s __attribute__((ext_vector_type(8)));
typedef float v4f __attribute__((ext_vector_type(4)));
typedef unsigned short v4u __attribute__((ext_vector_type(4)));
typedef unsigned int v2u __attribute__((ext_vector_type(2)));

__device__ __forceinline__ u16 f2bf(float f) {
  unsigned u = __builtin_bit_cast(unsigned, f);
  u += 0x7fffu + ((u >> 16) & 1u);
  return (u16)(u >> 16);
}
__device__ __forceinline__ float bf2f(u16 h) {
  unsigned u = ((unsigned)h) << 16;
  return __builtin_bit_cast(float, u);
}
__device__ __forceinline__ unsigned pk2(float a, float b) {
  return (unsigned)f2bf(a) | ((unsigned)f2bf(b) << 16);
}

// ---------------- cast fp32 -> bf16 (vectorized, G13) ----------------
__global__ void k_cast_bf16(const float* __restrict__ in, u16* __restrict__ out, int n4) {
  int i = blockIdx.x * blockDim.x + threadIdx.x;
  if (i >= n4) return;
  v4f v = ((const v4f*)in)[i];
  v4u o;
  o[0] = f2bf(v[0]); o[1] = f2bf(v[1]); o[2] = f2bf(v[2]); o[3] = f2bf(v[3]);
  ((v4u*)out)[i] = o;
}

// ---------------- fused cast of the 4 weight tensors ----------------
__global__ void k_cast_w(const float* __restrict__ a, const float* __restrict__ b,
                         const float* __restrict__ c, const float* __restrict__ d,
                         u16* __restrict__ oa, u16* __restrict__ ob, u16* __restrict__ oc,
                         u16* __restrict__ od, int na4, int nb4, int nc4, int nd4) {
  int j = blockIdx.x * blockDim.x + threadIdx.x;
  const float* src;
  u16* dst;
  if (j < na4) { src = a; dst = oa; }
  else {
    j -= na4;
    if (j < nb4) { src = b; dst = ob; }
    else {
      j -= nb4;
      if (j < nc4) { src = c; dst = oc; }
      else {
        j -= nc4;
        if (j >= nd4) return;
        src = d; dst = od;
      }
    }
  }
  v4f v = ((const v4f*)src)[j];
  v4u o;
  o[0] = f2bf(v[0]); o[1] = f2bf(v[1]); o[2] = f2bf(v[2]); o[3] = f2bf(v[3]);
  ((v4u*)dst)[j] = o;
}

// ---------------- RoPE cos/sin table [S][64] f32 ----------------
__global__ void k_rope_tab(float* __restrict__ cosT, float* __restrict__ sinT, float log2_base) {
  int idx = blockIdx.x * blockDim.x + threadIdx.x;
  int t = idx >> 6, i = idx & 63;
  float inv = exp2f(-(float)i * (1.0f / 64.0f) * log2_base);
  float fr = (float)t * inv;
  cosT[idx] = cosf(fr);
  sinT[idx] = sinf(fr);
}

// ------ per-head RMSNorm + RoPE + gain + output scale (in-place, bf16) -------
__global__ void k_rmsnorm_rope(u16* __restrict__ qk, const float* __restrict__ cosT,
                               const float* __restrict__ sinT, const float* __restrict__ gain,
                               int H, int S, float oscale) {
  int row = blockIdx.x * 4 + (threadIdx.x >> 6);
  int l = threadIdx.x & 63;
  int h = row % H;
  int m = row / H;
  int s = m % S;
  u16* p = qk + (size_t)row * 128;
  float a = bf2f(p[l]), b = bf2f(p[64 + l]);
  float ss = a * a + b * b;
#pragma unroll
  for (int o = 32; o; o >>= 1) ss += __shfl_xor(ss, o, 64);
  float r = rsqrtf(ss * (1.0f / 128.0f) + 1.1920929e-7f);
  a *= r; b *= r;
  float c = cosT[s * 64 + l], sn = sinT[s * 64 + l];
  float o1 = a * c + b * sn;
  float o2 = b * c - a * sn;
  float g = oscale;
  if (gain != nullptr) g *= gain[h];
  p[l] = f2bf(o1 * g);
  p[64 + l] = f2bf(o2 * g);
}

// -------- fused QKV GEMM: [M,2048]x[3072,2048]^T -> q/k/v_t (m97 + T1) -------
__global__ __launch_bounds__(256) void k_gemm_qkv(const u16* __restrict__ A,
                                                  const u16* __restrict__ Bw,
                                                  u16* __restrict__ q_o, u16* __restrict__ k_o,
                                                  u16* __restrict__ v_o, int M, int K) {
  __shared__ u16 sA[128 * 32];
  __shared__ u16 sB[128 * 32];
  const int tid = threadIdx.x;
  const int w = tid >> 6, l = tid & 63;
  const int lr = l & 15, lh = l >> 4;
  const int wr = w >> 1, wc = w & 1;
  const int nwg = gridDim.x * gridDim.y;
  const int bid = blockIdx.y * gridDim.x + blockIdx.x;
  const int cpx = nwg >> 3;
  const int swz = (bid & 7) * cpx + (bid >> 3);
  const int row0 = (swz / gridDim.x) * 128, col0 = (swz % gridDim.x) * 128;
  v4f zz = {0.f, 0.f, 0.f, 0.f};
  v4f acc[4][4];
#pragma unroll
  for (int mi = 0; mi < 4; ++mi)
#pragma unroll
    for (int ni = 0; ni < 4; ++ni) acc[mi][ni] = zz;

  const int lrow = l >> 2;
  const int lcol = (l & 3) * 8;

  for (int k0 = 0; k0 < K; k0 += 32) {
#pragma unroll
    for (int i = 0; i < 2; ++i) {
      int c = i * 4 + w;
      const u16* srcA = A + (size_t)(row0 + c * 16 + lrow) * K + (k0 + lcol);
      const u16* srcB = Bw + (size_t)(col0 + c * 16 + lrow) * K + (k0 + lcol);
      __builtin_amdgcn_global_load_lds((const __attribute__((address_space(1))) void*)srcA,
                                       (__attribute__((address_space(3))) void*)(sA + c * 512),
                                       16, 0, 0);
      __builtin_amdgcn_global_load_lds((const __attribute__((address_space(1))) void*)srcB,
                                       (__attribute__((address_space(3))) void*)(sB + c * 512),
                                       16, 0, 0);
    }
    __syncthreads();
    v8s af[4], bfr[4];
#pragma unroll
    for (int mi = 0; mi < 4; ++mi)
      af[mi] = *(const v8s*)(sA + (wr * 64 + mi * 16 + lr) * 32 + lh * 8);
#pragma unroll
    for (int ni = 0; ni < 4; ++ni)
      bfr[ni] = *(const v8s*)(sB + (wc * 64 + ni * 16 + lr) * 32 + lh * 8);
#pragma unroll
    for (int mi = 0; mi < 4; ++mi)
#pragma unroll
      for (int ni = 0; ni < 4; ++ni)
        acc[mi][ni] = __builtin_amdgcn_mfma_f32_16x16x32_bf16(af[mi], bfr[ni], acc[mi][ni], 0, 0, 0);
    __syncthreads();
  }
  u16* outp;
  int ldo = 0, cb;
  bool tr = false;
  if (col0 < 2048) { outp = q_o; ldo = 2048; cb = col0; }
  else if (col0 < 2560) { outp = k_o; ldo = 512; cb = col0 - 2048; }
  else { outp = v_o; tr = true; cb = col0 - 2560; }
#pragma unroll
  for (int mi = 0; mi < 4; ++mi) {
#pragma unroll
    for (int ni = 0; ni < 4; ++ni) {
      int row = row0 + wr * 64 + mi * 16 + lh * 4;
      int col = cb + wc * 64 + ni * 16 + lr;
#pragma unroll
      for (int r = 0; r < 4; ++r) {
        u16 bv = f2bf(acc[mi][ni][r]);
        if (tr) outp[(size_t)col * M + row + r] = bv;
        else    outp[(size_t)(row + r) * ldo + col] = bv;
      }
    }
  }
}

// ---------------- out-proj GEMM: C[M,N] = A[M,K] * Bw[N,K]^T (m97 + T1) ------
__global__ __launch_bounds__(256) void k_gemm_bt(const u16* __restrict__ A,
                                                 const u16* __restrict__ Bw,
                                                 float* __restrict__ C, int M, int N, int K) {
  __shared__ u16 sA[128 * 32];
  __shared__ u16 sB[128 * 32];
  const int tid = threadIdx.x;
  const int w = tid >> 6, l = tid & 63;
  const int lr = l & 15, lh = l >> 4;
  const int wr = w >> 1, wc = w & 1;
  const int nwg = gridDim.x * gridDim.y;
  const int bid = blockIdx.y * gridDim.x + blockIdx.x;
  const int cpx = nwg >> 3;
  const int swz = (bid & 7) * cpx + (bid >> 3);
  const int row0 = (swz / gridDim.x) * 128, col0 = (swz % gridDim.x) * 128;
  v4f zz = {0.f, 0.f, 0.f, 0.f};
  v4f acc[4][4];
#pragma unroll
  for (int mi = 0; mi < 4; ++mi)
#pragma unroll
    for (int ni = 0; ni < 4; ++ni) acc[mi][ni] = zz;

  const int lrow = l >> 2;
  const int lcol = (l & 3) * 8;

  for (int k0 = 0; k0 < K; k0 += 32) {
#pragma unroll
    for (int i = 0; i < 2; ++i) {
      int c = i * 4 + w;
      const u16* srcA = A + (size_t)(row0 + c * 16 + lrow) * K + (k0 + lcol);
      const u16* srcB = Bw + (size_t)(col0 + c * 16 + lrow) * K + (k0 + lcol);
      __builtin_amdgcn_global_load_lds((const __attribute__((address_space(1))) void*)srcA,
                                       (__attribute__((address_space(3))) void*)(sA + c * 512),
                                       16, 0, 0);
      __builtin_amdgcn_global_load_lds((const __attribute__((address_space(1))) void*)srcB,
                                       (__attribute__((address_space(3))) void*)(sB + c * 512),
                                       16, 0, 0);
    }
    __syncthreads();
    v8s af[4], bfr[4];
#pragma unroll
    for (int mi = 0; mi < 4; ++mi)
      af[mi] = *(const v8s*)(sA + (wr * 64 + mi * 16 + lr) * 32 + lh * 8);
#pragma unroll
    for (int ni = 0; ni < 4; ++ni)
      bfr[ni] = *(const v8s*)(sB + (wc * 64 + ni * 16 + lr) * 32 + lh * 8);
#pragma unroll
    for (int mi = 0; mi < 4; ++mi)
#pragma unroll
      for (int ni = 0; ni < 4; ++ni)
        acc[mi][ni] = __builtin_amdgcn_mfma_f32_16x16x32_bf16(af[mi], bfr[ni], acc[mi][ni], 0, 0, 0);
    __syncthreads();
  }
#pragma unroll
  for (int mi = 0; mi < 4; ++mi) {
#pragma unroll
    for (int ni = 0; ni < 4; ++ni) {
      int row = row0 + wr * 64 + mi * 16 + lh * 4;
      int col = col0 + wc * 64 + ni * 16 + lr;
#pragma unroll
      for (int r = 0; r < 4; ++r) C[(size_t)(row + r) * N + col] = acc[mi][ni][r];
    }
  }
}

// ---------------- causal GQA flash attention v6 (balanced KV-split) ----------
// grid (B*H, 32). slot<16: head piece of qt=16+slot, kv [0,16) -> partial 0 (16u).
// slot>=16: tail piece of qt=16+s, kv [16,qt+1) -> partial 1, then full short
// q-tile qt'=15-s -> final (17u total). 1024 blocks, all ~equal, 4/CU resident.
__global__ __launch_bounds__(256, 4) void k_flash_attn(
    const u16* __restrict__ Q, const u16* __restrict__ Kb, const u16* __restrict__ Vt,
    u16* __restrict__ O, u16* __restrict__ o_part, float* __restrict__ m_part,
    float* __restrict__ l_part, int S, int H, int KH, int Mtot) {
  const int bh = blockIdx.x;
  const int slot = blockIdx.y;
  const int h = bh % H, b = bh / H;
  const int kvh = h / (H / KH);
  const int w = threadIdx.x >> 6, l = threadIdx.x & 63;
  const int lr = l & 15, lh = l >> 4;

  __shared__ alignas(16) char sK[2][16384];           // 64 kv-rows x 256B, swizzled
  __shared__ alignas(16) unsigned P_lds[4][16 * 32];  // per-wave packed P, XOR-swizzled
  unsigned* prow = P_lds[w] + lr * 32;
  const int xr = (lr & 7) << 2;

  v4f zz = {0.f, 0.f, 0.f, 0.f};
  const int strideK = KH * 128;
  const int strideKB = strideK * 2;
  const char* KheadB = (const char*)Kb + 2 * ((size_t)b * S * strideK + (size_t)kvh * 128);
  const u16* Vbase = Vt + (size_t)(kvh * 128) * Mtot + (size_t)b * S;

  // per-segment body; fin/pidx are compile-time at each call site
  auto run = [&](int qt, int t0, int t1, bool fin, int pidx) {
    const int q0 = qt * 64;
    const int qi = q0 + w * 16 + lr;

    v8s qf[4];
    const u16* qp = Q + (size_t)(b * S + q0 + w * 16 + lr) * (size_t)(H * 128) + h * 128 + lh * 8;
#pragma unroll
    for (int c = 0; c < 4; ++c) qf[c] = *(const v8s*)(qp + c * 32);

    v4f o_acc[8];
#pragma unroll
    for (int df = 0; df < 8; ++df) o_acc[df] = zz;
    float m_run = -1e30f, l_run = 0.f;

    // prologue: stage tile t0 into buf 0
    {
      const char* Kt = KheadB + (size_t)(t0 * 64) * strideKB;
#pragma unroll
      for (int j = 0; j < 4; ++j) {
        int jj = w * 4 + j;
        int ci = jj * 64 + l;
        int r = ci >> 4;
        int bc = (ci & 15) << 4;
        const char* src = Kt + (size_t)r * strideKB + (bc ^ ((r & 15) << 4));
        __builtin_amdgcn_global_load_lds((const __attribute__((address_space(1))) void*)src,
                                         (__attribute__((address_space(3))) void*)(sK[0] + jj * 1024),
                                         16, 0, 0);
      }
    }
    __syncthreads();

    int buf = 0;
    for (int t = t0; t < t1; ++t) {
      const int kv0 = t * 64;
      const bool lastTile = (t == t1 - 1);
      const char* sKb = sK[buf];

      v4f sv[4];
      __builtin_amdgcn_s_setprio(1);
#pragma unroll
      for (int nf = 0; nf < 4; ++nf) {
        v4f a_ = zz;
        const int r = nf * 16 + lr;
#pragma unroll
        for (int c = 0; c < 4; ++c) {
          v8s kf = *(const v8s*)(sKb + r * 256 + ((lh * 16 + c * 64) ^ (lr << 4)));
          a_ = __builtin_amdgcn_mfma_f32_16x16x32_bf16(kf, qf[c], a_, 0, 0, 0);
        }
        sv[nf] = a_;
      }
      __builtin_amdgcn_s_setprio(0);

      v8s vf[8][2];
#pragma unroll
      for (int df = 0; df < 8; ++df) {
        const u16* vp = Vbase + (size_t)(df * 16 + lr) * Mtot + kv0 + lh * 8;
#pragma unroll
        for (int c2 = 0; c2 < 2; ++c2) vf[df][c2] = *(const v8s*)(vp + c2 * 32);
      }

      if (t + 1 < t1) {
        const char* Kt = KheadB + (size_t)(kv0 + 64) * strideKB;
        char* dst = (char*)sK[buf ^ 1];
#pragma unroll
        for (int j = 0; j < 4; ++j) {
          int jj = w * 4 + j;
          int ci = jj * 64 + l;
          int r = ci >> 4;
          int bc = (ci & 15) << 4;
          const char* src = Kt + (size_t)r * strideKB + (bc ^ ((r & 15) << 4));
          __builtin_amdgcn_global_load_lds((const __attribute__((address_space(1))) void*)src,
                                           (__attribute__((address_space(3))) void*)(dst + jj * 1024),
                                           16, 0, 0);
        }
      }

      if (lastTile) {  // no-op for head pieces (kv always <= qi there)
#pragma unroll
        for (int nf = 0; nf < 4; ++nf)
#pragma unroll
          for (int r = 0; r < 4; ++r)
            if (kv0 + nf * 16 + lh * 4 + r > qi) sv[nf][r] = -1e30f;
      }
      float pmax = -1e30f;
#pragma unroll
      for (int nf = 0; nf < 4; ++nf)
#pragma unroll
        for (int r = 0; r < 4; ++r) pmax = fmaxf(pmax, sv[nf][r]);
      pmax = fmaxf(pmax, __shfl_xor(pmax, 16, 64));
      pmax = fmaxf(pmax, __shfl_xor(pmax, 32, 64));
      if (!__all(pmax - m_run <= 8.0f)) {  // T13 defer-max
        float mnew = fmaxf(m_run, pmax);
        float corr = exp2f(m_run - mnew);
        l_run *= corr;
        m_run = mnew;
        float corrq[4];
#pragma unroll
        for (int r = 0; r < 4; ++r) corrq[r] = __shfl(corr, lh * 4 + r, 16);
#pragma unroll
        for (int df = 0; df < 8; ++df)
#pragma unroll
          for (int r = 0; r < 4; ++r) o_acc[df][r] *= corrq[r];
      }
      float rsum = 0.f;
#pragma unroll
      for (int nf = 0; nf < 4; ++nf)
#pragma unroll
        for (int r = 0; r < 4; ++r) {
          float pv = exp2f(sv[nf][r] - m_run);
          sv[nf][r] = pv;
          rsum += pv;
        }
      rsum += __shfl_xor(rsum, 16, 64);
      rsum += __shfl_xor(rsum, 32, 64);
      l_run += rsum;

#pragma unroll
      for (int nf = 0; nf < 4; ++nf) {
        v2u pw;
        pw[0] = pk2(sv[nf][0], sv[nf][1]);
        pw[1] = pk2(sv[nf][2], sv[nf][3]);
        *(v2u*)(prow + ((nf * 8 + lh * 2) ^ xr)) = pw;
      }
      asm volatile("s_waitcnt lgkmcnt(0)" ::: "memory");
      __builtin_amdgcn_sched_barrier(0);  // rule 18
      v8s ap[2];
#pragma unroll
      for (int c2 = 0; c2 < 2; ++c2) ap[c2] = *(const v8s*)(prow + ((c2 * 16 + lh * 4) ^ xr));

      __builtin_amdgcn_s_setprio(1);
#pragma unroll
      for (int df = 0; df < 8; ++df)
#pragma unroll
        for (int c2 = 0; c2 < 2; ++c2)
          o_acc[df] = __builtin_amdgcn_mfma_f32_16x16x32_bf16(ap[c2], vf[df][c2], o_acc[df], 0, 0, 0);
      __builtin_amdgcn_s_setprio(0);

      __syncthreads();
      buf ^= 1;
    }

    if (fin) {
      float rl = 1.0f / l_run;
      float invq[4];
#pragma unroll
      for (int r = 0; r < 4; ++r) invq[r] = __shfl(rl, lh * 4 + r, 16);
      u16* op = O + (size_t)(b * S + q0 + w * 16 + lh * 4) * (size_t)(H * 128) + h * 128;
#pragma unroll
      for (int r = 0; r < 4; ++r)
#pragma unroll
        for (int df = 0; df < 8; ++df)
          op[(size_t)r * (H * 128) + df * 16 + lr] = f2bf(o_acc[df][r] * invq[r]);
    } else {
      const size_t idx = ((size_t)(pidx * 32 + bh) * 16 + (qt - 16));
      u16* op = o_part + idx * 8192 + (size_t)(w * 16 + lh * 4) * 128;
#pragma unroll
      for (int r = 0; r < 4; ++r)
#pragma unroll
        for (int df = 0; df < 8; ++df)
          op[(size_t)r * 128 + df * 16 + lr] = f2bf(o_acc[df][r]);
      if (lh == 0) {
        size_t mi = idx * 64 + (w * 16 + lr);
        m_part[mi] = m_run;
        l_part[mi] = l_run;
      }
    }
  };

  if (slot < 16) {
    run(16 + slot, 0, 16, false, 0);  // head piece: 16 units, no diagonal
  } else {
    const int s = slot - 16;
    run(16 + s, 16, 16 + s + 1, false, 1);  // tail piece: s+1 units (diagonal)
    run(15 - s, 0, 16 - s, true, 0);        // short q-tile: 16-s units (final)
  }
}

// ---------------- merge the two partials of each long q-tile ----------------
__global__ __launch_bounds__(256) void k_merge(const u16* __restrict__ o_part,
                                               const float* __restrict__ m_part,
                                               const float* __restrict__ l_part,
                                               u16* __restrict__ ao, int S, int H) {
  const int bh = blockIdx.x;  // 32
  const int j = blockIdx.y;   // 16
  const int h = bh % H, b = bh / H;
  const int q0 = (16 + j) * 64;
  const int tid = threadIdx.x;
  const size_t i0 = (size_t)bh * 16 + j;
  const size_t i1 = (size_t)(32 + bh) * 16 + j;
#pragma unroll
  for (int i = 0; i < 4; ++i) {
    int c = i * 256 + tid;  // 0..1023
    int row = c >> 4, c8 = c & 15;
    float m0 = m_part[i0 * 64 + row], m1 = m_part[i1 * 64 + row];
    float l0 = l_part[i0 * 64 + row], l1 = l_part[i1 * 64 + row];
    float m = fmaxf(m0, m1);
    float a0 = exp2f(m0 - m), a1 = exp2f(m1 - m);
    float inv = 1.0f / (l0 * a0 + l1 * a1);
    a0 *= inv; a1 *= inv;
    v8s x0 = *(const v8s*)(o_part + i0 * 8192 + row * 128 + c8 * 8);
    v8s x1 = *(const v8s*)(o_part + i1 * 8192 + row * 128 + c8 * 8);
    v8s res;
#pragma unroll
    for (int e = 0; e < 8; ++e)
      res[e] = (short)f2bf(bf2f((u16)x0[e]) * a0 + bf2f((u16)x1[e]) * a1);
    *(v8s*)(ao + (size_t)(b * S + q0 + row) * (size_t)(H * 128) + h * 128 + c8 * 8) = res;
  }
}

extern "C" void kernel_launch(void* const* d_in, const int* in_sizes, int n_in, void* d_out,
                              int out_size, void* d_ws, size_t ws_size, hipStream_t stream) {
  const float* x = (const float*)d_in[0];
  const float* Wq = (const float*)d_in[1];
  const float* Wk = (const float*)d_in[2];
  const float* Wv = (const float*)d_in[3];
  const float* Wp = (const float*)d_in[4];
  const float* gain = (const float*)d_in[5];
  float* out = (float*)d_out;

  const int B = 2, S = 2048, D = 2048, H = 16, KH = 4;
  const int M = B * S;
  const int KVD = KH * 128;
  const int NQKV = D + 2 * KVD;  // 3072

  char* w = (char*)d_ws;
  u16* x_bf = (u16*)w;   w += (size_t)M * D * 2;
  u16* wqkv = (u16*)w;   w += (size_t)NQKV * D * 2;
  u16* wp_bf = (u16*)w;  w += (size_t)D * D * 2;
  u16* q_bf = (u16*)w;   w += (size_t)M * D * 2;
  u16* k_bf = (u16*)w;   w += (size_t)M * KVD * 2;
  u16* v_t = (u16*)w;    w += (size_t)M * KVD * 2;
  u16* ao_bf = (u16*)w;  w += (size_t)M * D * 2;
  float* cosT = (float*)w; w += (size_t)S * 64 * 4;
  float* sinT = (float*)w; w += (size_t)S * 64 * 4;
  if ((size_t)(w - (char*)d_ws) > ws_size) return;
  // attention partials alias regions dead after the QKV GEMM:
  u16* o_part = x_bf;          // 2*32*16*8192 u16 = 16.78 MB == x_bf region
  float* m_part = (float*)wqkv;        // 256 KB
  float* l_part = m_part + 2 * 32 * 16 * 64;  // 256 KB

  k_cast_bf16<<<(M * D / 4 + 255) / 256, 256, 0, stream>>>(x, x_bf, M * D / 4);
  {
    int na4 = D * D / 4, nb4 = KVD * D / 4, nc4 = KVD * D / 4, nd4 = D * D / 4;
    int tot = na4 + nb4 + nc4 + nd4;
    k_cast_w<<<(tot + 255) / 256, 256, 0, stream>>>(
        Wq, Wk, Wv, Wp, wqkv, wqkv + (size_t)D * D, wqkv + (size_t)(D + KVD) * D, wp_bf,
        na4, nb4, nc4, nd4);
  }

  double scale = (double)S / 1024.0;
  double base = (S > 1024) ? 10000.0 * pow(scale, 128.0 / 126.0) : 10000.0;
  float l2b = (float)(log(base) / log(2.0));
  k_rope_tab<<<S * 64 / 256, 256, 0, stream>>>(cosT, sinT, l2b);

  dim3 blk(256);
  dim3 gqkv(NQKV / 128, M / 128);  // 24 x 32 = 768 blocks
  k_gemm_qkv<<<gqkv, blk, 0, stream>>>(x_bf, wqkv, q_bf, k_bf, v_t, M, D);

  float qscale = 1.4426950408889634f / sqrtf(128.0f);
  k_rmsnorm_rope<<<(M * H) / 4, 256, 0, stream>>>(q_bf, cosT, sinT, gain, H, S, qscale);
  k_rmsnorm_rope<<<(M * KH) / 4, 256, 0, stream>>>(k_bf, cosT, sinT, nullptr, KH, S, 1.0f);

  dim3 ga(B * H, 32);  // 1024 balanced blocks (16-17 tile-units each)
  k_flash_attn<<<ga, blk, 0, stream>>>(q_bf, k_bf, v_t, ao_bf, o_part, m_part, l_part,
                                       S, H, KH, M);
  dim3 gm(B * H, 16);
  k_merge<<<gm, blk, 0, stream>>>(o_part, m_part, l_part, ao_bf, S, H);

  dim3 gp(D / 128, M / 128);
  k_gemm_bt<<<gp, blk, 0, stream>>>(ao_bf, wp_bf, out, M, D, D);
}

// Round 7
// 369.430 us; speedup vs baseline: 1.3031x; 1.3031x over previous
//
#include <hip/hip_runtime.h>
#include <cmath>

typedef unsigned short u16;
typedef short v8s __attribute__((ext_vector_type(8)));
typedef float v4f __attribute__((ext_vector_type(4)));
typedef unsigned short v4u __attribute__((ext_vector_type(4)));
typedef unsigned int v2u __attribute__((ext_vector_type(2)));

__device__ __forceinline__ u16 f2bf(float f) {
  unsigned u = __builtin_bit_cast(unsigned, f);
  u += 0x7fffu + ((u >> 16) & 1u);
  return (u16)(u >> 16);
}
__device__ __forceinline__ float bf2f(u16 h) {
  unsigned u = ((unsigned)h) << 16;
  return __builtin_bit_cast(float, u);
}
__device__ __forceinline__ unsigned pk2(float a, float b) {
  return (unsigned)f2bf(a) | ((unsigned)f2bf(b) << 16);
}

// ---------------- cast fp32 -> bf16 (vectorized, G13) ----------------
__global__ void k_cast_bf16(const float* __restrict__ in, u16* __restrict__ out, int n4) {
  int i = blockIdx.x * blockDim.x + threadIdx.x;
  if (i >= n4) return;
  v4f v = ((const v4f*)in)[i];
  v4u o;
  o[0] = f2bf(v[0]); o[1] = f2bf(v[1]); o[2] = f2bf(v[2]); o[3] = f2bf(v[3]);
  ((v4u*)out)[i] = o;
}

// ---------------- fused cast of the 4 weight tensors ----------------
__global__ void k_cast_w(const float* __restrict__ a, const float* __restrict__ b,
                         const float* __restrict__ c, const float* __restrict__ d,
                         u16* __restrict__ oa, u16* __restrict__ ob, u16* __restrict__ oc,
                         u16* __restrict__ od, int na4, int nb4, int nc4, int nd4) {
  int j = blockIdx.x * blockDim.x + threadIdx.x;
  const float* src;
  u16* dst;
  if (j < na4) { src = a; dst = oa; }
  else {
    j -= na4;
    if (j < nb4) { src = b; dst = ob; }
    else {
      j -= nb4;
      if (j < nc4) { src = c; dst = oc; }
      else {
        j -= nc4;
        if (j >= nd4) return;
        src = d; dst = od;
      }
    }
  }
  v4f v = ((const v4f*)src)[j];
  v4u o;
  o[0] = f2bf(v[0]); o[1] = f2bf(v[1]); o[2] = f2bf(v[2]); o[3] = f2bf(v[3]);
  ((v4u*)dst)[j] = o;
}

// ---------------- RoPE cos/sin table [S][64] f32 ----------------
__global__ void k_rope_tab(float* __restrict__ cosT, float* __restrict__ sinT, float log2_base) {
  int idx = blockIdx.x * blockDim.x + threadIdx.x;
  int t = idx >> 6, i = idx & 63;
  float inv = exp2f(-(float)i * (1.0f / 64.0f) * log2_base);
  float fr = (float)t * inv;
  cosT[idx] = cosf(fr);
  sinT[idx] = sinf(fr);
}

// ------ per-head RMSNorm + RoPE + gain + output scale (in-place, bf16) -------
__global__ void k_rmsnorm_rope(u16* __restrict__ qk, const float* __restrict__ cosT,
                               const float* __restrict__ sinT, const float* __restrict__ gain,
                               int H, int S, float oscale) {
  int row = blockIdx.x * 4 + (threadIdx.x >> 6);
  int l = threadIdx.x & 63;
  int h = row % H;
  int m = row / H;
  int s = m % S;
  u16* p = qk + (size_t)row * 128;
  float a = bf2f(p[l]), b = bf2f(p[64 + l]);
  float ss = a * a + b * b;
#pragma unroll
  for (int o = 32; o; o >>= 1) ss += __shfl_xor(ss, o, 64);
  float r = rsqrtf(ss * (1.0f / 128.0f) + 1.1920929e-7f);
  a *= r; b *= r;
  float c = cosT[s * 64 + l], sn = sinT[s * 64 + l];
  float o1 = a * c + b * sn;
  float o2 = b * c - a * sn;
  float g = oscale;
  if (gain != nullptr) g *= gain[h];
  p[l] = f2bf(o1 * g);
  p[64 + l] = f2bf(o2 * g);
}

// -------- fused QKV GEMM: [M,2048]x[3072,2048]^T -> q/k/v_t (m97 + T1) -------
__global__ __launch_bounds__(256) void k_gemm_qkv(const u16* __restrict__ A,
                                                  const u16* __restrict__ Bw,
                                                  u16* __restrict__ q_o, u16* __restrict__ k_o,
                                                  u16* __restrict__ v_o, int M, int K) {
  __shared__ u16 sA[128 * 32];
  __shared__ u16 sB[128 * 32];
  const int tid = threadIdx.x;
  const int w = tid >> 6, l = tid & 63;
  const int lr = l & 15, lh = l >> 4;
  const int wr = w >> 1, wc = w & 1;
  const int nwg = gridDim.x * gridDim.y;
  const int bid = blockIdx.y * gridDim.x + blockIdx.x;
  const int cpx = nwg >> 3;
  const int swz = (bid & 7) * cpx + (bid >> 3);
  const int row0 = (swz / gridDim.x) * 128, col0 = (swz % gridDim.x) * 128;
  v4f zz = {0.f, 0.f, 0.f, 0.f};
  v4f acc[4][4];
#pragma unroll
  for (int mi = 0; mi < 4; ++mi)
#pragma unroll
    for (int ni = 0; ni < 4; ++ni) acc[mi][ni] = zz;

  const int lrow = l >> 2;
  const int lcol = (l & 3) * 8;

  for (int k0 = 0; k0 < K; k0 += 32) {
#pragma unroll
    for (int i = 0; i < 2; ++i) {
      int c = i * 4 + w;
      const u16* srcA = A + (size_t)(row0 + c * 16 + lrow) * K + (k0 + lcol);
      const u16* srcB = Bw + (size_t)(col0 + c * 16 + lrow) * K + (k0 + lcol);
      __builtin_amdgcn_global_load_lds((const __attribute__((address_space(1))) void*)srcA,
                                       (__attribute__((address_space(3))) void*)(sA + c * 512),
                                       16, 0, 0);
      __builtin_amdgcn_global_load_lds((const __attribute__((address_space(1))) void*)srcB,
                                       (__attribute__((address_space(3))) void*)(sB + c * 512),
                                       16, 0, 0);
    }
    __syncthreads();
    v8s af[4], bfr[4];
#pragma unroll
    for (int mi = 0; mi < 4; ++mi)
      af[mi] = *(const v8s*)(sA + (wr * 64 + mi * 16 + lr) * 32 + lh * 8);
#pragma unroll
    for (int ni = 0; ni < 4; ++ni)
      bfr[ni] = *(const v8s*)(sB + (wc * 64 + ni * 16 + lr) * 32 + lh * 8);
#pragma unroll
    for (int mi = 0; mi < 4; ++mi)
#pragma unroll
      for (int ni = 0; ni < 4; ++ni)
        acc[mi][ni] = __builtin_amdgcn_mfma_f32_16x16x32_bf16(af[mi], bfr[ni], acc[mi][ni], 0, 0, 0);
    __syncthreads();
  }
  u16* outp;
  int ldo = 0, cb;
  bool tr = false;
  if (col0 < 2048) { outp = q_o; ldo = 2048; cb = col0; }
  else if (col0 < 2560) { outp = k_o; ldo = 512; cb = col0 - 2048; }
  else { outp = v_o; tr = true; cb = col0 - 2560; }
#pragma unroll
  for (int mi = 0; mi < 4; ++mi) {
#pragma unroll
    for (int ni = 0; ni < 4; ++ni) {
      int row = row0 + wr * 64 + mi * 16 + lh * 4;
      int col = cb + wc * 64 + ni * 16 + lr;
#pragma unroll
      for (int r = 0; r < 4; ++r) {
        u16 bv = f2bf(acc[mi][ni][r]);
        if (tr) outp[(size_t)col * M + row + r] = bv;
        else    outp[(size_t)(row + r) * ldo + col] = bv;
      }
    }
  }
}

// ---------------- out-proj GEMM: C[M,N] = A[M,K] * Bw[N,K]^T (m97 + T1) ------
__global__ __launch_bounds__(256) void k_gemm_bt(const u16* __restrict__ A,
                                                 const u16* __restrict__ Bw,
                                                 float* __restrict__ C, int M, int N, int K) {
  __shared__ u16 sA[128 * 32];
  __shared__ u16 sB[128 * 32];
  const int tid = threadIdx.x;
  const int w = tid >> 6, l = tid & 63;
  const int lr = l & 15, lh = l >> 4;
  const int wr = w >> 1, wc = w & 1;
  const int nwg = gridDim.x * gridDim.y;
  const int bid = blockIdx.y * gridDim.x + blockIdx.x;
  const int cpx = nwg >> 3;
  const int swz = (bid & 7) * cpx + (bid >> 3);
  const int row0 = (swz / gridDim.x) * 128, col0 = (swz % gridDim.x) * 128;
  v4f zz = {0.f, 0.f, 0.f, 0.f};
  v4f acc[4][4];
#pragma unroll
  for (int mi = 0; mi < 4; ++mi)
#pragma unroll
    for (int ni = 0; ni < 4; ++ni) acc[mi][ni] = zz;

  const int lrow = l >> 2;
  const int lcol = (l & 3) * 8;

  for (int k0 = 0; k0 < K; k0 += 32) {
#pragma unroll
    for (int i = 0; i < 2; ++i) {
      int c = i * 4 + w;
      const u16* srcA = A + (size_t)(row0 + c * 16 + lrow) * K + (k0 + lcol);
      const u16* srcB = Bw + (size_t)(col0 + c * 16 + lrow) * K + (k0 + lcol);
      __builtin_amdgcn_global_load_lds((const __attribute__((address_space(1))) void*)srcA,
                                       (__attribute__((address_space(3))) void*)(sA + c * 512),
                                       16, 0, 0);
      __builtin_amdgcn_global_load_lds((const __attribute__((address_space(1))) void*)srcB,
                                       (__attribute__((address_space(3))) void*)(sB + c * 512),
                                       16, 0, 0);
    }
    __syncthreads();
    v8s af[4], bfr[4];
#pragma unroll
    for (int mi = 0; mi < 4; ++mi)
      af[mi] = *(const v8s*)(sA + (wr * 64 + mi * 16 + lr) * 32 + lh * 8);
#pragma unroll
    for (int ni = 0; ni < 4; ++ni)
      bfr[ni] = *(const v8s*)(sB + (wc * 64 + ni * 16 + lr) * 32 + lh * 8);
#pragma unroll
    for (int mi = 0; mi < 4; ++mi)
#pragma unroll
      for (int ni = 0; ni < 4; ++ni)
        acc[mi][ni] = __builtin_amdgcn_mfma_f32_16x16x32_bf16(af[mi], bfr[ni], acc[mi][ni], 0, 0, 0);
    __syncthreads();
  }
#pragma unroll
  for (int mi = 0; mi < 4; ++mi) {
#pragma unroll
    for (int ni = 0; ni < 4; ++ni) {
      int row = row0 + wr * 64 + mi * 16 + lh * 4;
      int col = col0 + wc * 64 + ni * 16 + lr;
#pragma unroll
      for (int r = 0; r < 4; ++r) C[(size_t)(row + r) * N + col] = acc[mi][ni][r];
    }
  }
}

// ---------------- causal GQA flash attention v7 (balanced KV-split, flat) ----
// grid (B*H, 32). slot<16: head piece of qt=16+slot, kv [0,16) (16u).
// slot>=16 (s=slot-16): seg0 = tail piece of qt=16+s, kv [16,17+s) (s+1 u),
// seg1 = full short q-tile qt'=15-s (16-s u, final). Segments run in a
// RUNTIME loop so the body inlines ONCE (R6's double-inline + VGPR clamp
// caused catastrophic spills: VGPR 64, 498MB scratch fetch).
__global__ __launch_bounds__(256) void k_flash_attn(
    const u16* __restrict__ Q, const u16* __restrict__ Kb, const u16* __restrict__ Vt,
    u16* __restrict__ O, u16* __restrict__ o_part, float* __restrict__ m_part,
    float* __restrict__ l_part, int S, int H, int KH, int Mtot) {
  const int bh = blockIdx.x;
  const int slot = blockIdx.y;
  const int h = bh % H, b = bh / H;
  const int kvh = h / (H / KH);
  const int w = threadIdx.x >> 6, l = threadIdx.x & 63;
  const int lr = l & 15, lh = l >> 4;

  __shared__ alignas(16) char sK[2][16384];           // 64 kv-rows x 256B, swizzled
  __shared__ alignas(16) unsigned P_lds[4][16 * 32];  // per-wave packed P, XOR-swizzled
  unsigned* prow = P_lds[w] + lr * 32;
  const int xr = (lr & 7) << 2;

  v4f zz = {0.f, 0.f, 0.f, 0.f};
  const int strideK = KH * 128;
  const int strideKB = strideK * 2;
  const char* KheadB = (const char*)Kb + 2 * ((size_t)b * S * strideK + (size_t)kvh * 128);
  const u16* Vbase = Vt + (size_t)(kvh * 128) * Mtot + (size_t)b * S;

  const int nseg = (slot < 16) ? 1 : 2;
  for (int seg = 0; seg < nseg; ++seg) {
    // segment descriptor (scalar branches, no arrays -> no scratch)
    int qt, t0, t1, pidx;
    bool fin;
    if (slot < 16) {
      qt = 16 + slot; t0 = 0; t1 = 16; fin = false; pidx = 0;
    } else {
      const int s = slot - 16;
      if (seg == 0) { qt = 16 + s; t0 = 16; t1 = 17 + s; fin = false; pidx = 1; }
      else          { qt = 15 - s; t0 = 0;  t1 = 16 - s; fin = true;  pidx = 0; }
    }
    const int q0 = qt * 64;
    const int qi = q0 + w * 16 + lr;

    v8s qf[4];
    const u16* qp = Q + (size_t)(b * S + q0 + w * 16 + lr) * (size_t)(H * 128) + h * 128 + lh * 8;
#pragma unroll
    for (int c = 0; c < 4; ++c) qf[c] = *(const v8s*)(qp + c * 32);

    v4f o_acc[8];
#pragma unroll
    for (int df = 0; df < 8; ++df) o_acc[df] = zz;
    float m_run = -1e30f, l_run = 0.f;

    // prologue: stage tile t0 into buf 0
    {
      const char* Kt = KheadB + (size_t)(t0 * 64) * strideKB;
#pragma unroll
      for (int j = 0; j < 4; ++j) {
        int jj = w * 4 + j;
        int ci = jj * 64 + l;
        int r = ci >> 4;
        int bc = (ci & 15) << 4;
        const char* src = Kt + (size_t)r * strideKB + (bc ^ ((r & 15) << 4));
        __builtin_amdgcn_global_load_lds((const __attribute__((address_space(1))) void*)src,
                                         (__attribute__((address_space(3))) void*)(sK[0] + jj * 1024),
                                         16, 0, 0);
      }
    }
    __syncthreads();

    int buf = 0;
    for (int t = t0; t < t1; ++t) {
      const int kv0 = t * 64;
      const bool lastTile = (t == t1 - 1);
      const char* sKb = sK[buf];

      v4f sv[4];
      __builtin_amdgcn_s_setprio(1);
#pragma unroll
      for (int nf = 0; nf < 4; ++nf) {
        v4f a_ = zz;
        const int r = nf * 16 + lr;
#pragma unroll
        for (int c = 0; c < 4; ++c) {
          v8s kf = *(const v8s*)(sKb + r * 256 + ((lh * 16 + c * 64) ^ (lr << 4)));
          a_ = __builtin_amdgcn_mfma_f32_16x16x32_bf16(kf, qf[c], a_, 0, 0, 0);
        }
        sv[nf] = a_;
      }
      __builtin_amdgcn_s_setprio(0);

      v8s vf[8][2];
#pragma unroll
      for (int df = 0; df < 8; ++df) {
        const u16* vp = Vbase + (size_t)(df * 16 + lr) * Mtot + kv0 + lh * 8;
#pragma unroll
        for (int c2 = 0; c2 < 2; ++c2) vf[df][c2] = *(const v8s*)(vp + c2 * 32);
      }

      if (t + 1 < t1) {
        const char* Kt = KheadB + (size_t)(kv0 + 64) * strideKB;
        char* dst = (char*)sK[buf ^ 1];
#pragma unroll
        for (int j = 0; j < 4; ++j) {
          int jj = w * 4 + j;
          int ci = jj * 64 + l;
          int r = ci >> 4;
          int bc = (ci & 15) << 4;
          const char* src = Kt + (size_t)r * strideKB + (bc ^ ((r & 15) << 4));
          __builtin_amdgcn_global_load_lds((const __attribute__((address_space(1))) void*)src,
                                           (__attribute__((address_space(3))) void*)(dst + jj * 1024),
                                           16, 0, 0);
        }
      }

      if (lastTile) {  // no-op for head pieces (kv always <= qi there)
#pragma unroll
        for (int nf = 0; nf < 4; ++nf)
#pragma unroll
          for (int r = 0; r < 4; ++r)
            if (kv0 + nf * 16 + lh * 4 + r > qi) sv[nf][r] = -1e30f;
      }
      float pmax = -1e30f;
#pragma unroll
      for (int nf = 0; nf < 4; ++nf)
#pragma unroll
        for (int r = 0; r < 4; ++r) pmax = fmaxf(pmax, sv[nf][r]);
      pmax = fmaxf(pmax, __shfl_xor(pmax, 16, 64));
      pmax = fmaxf(pmax, __shfl_xor(pmax, 32, 64));
      if (!__all(pmax - m_run <= 8.0f)) {  // T13 defer-max
        float mnew = fmaxf(m_run, pmax);
        float corr = exp2f(m_run - mnew);
        l_run *= corr;
        m_run = mnew;
        float corrq[4];
#pragma unroll
        for (int r = 0; r < 4; ++r) corrq[r] = __shfl(corr, lh * 4 + r, 16);
#pragma unroll
        for (int df = 0; df < 8; ++df)
#pragma unroll
          for (int r = 0; r < 4; ++r) o_acc[df][r] *= corrq[r];
      }
      float rsum = 0.f;
#pragma unroll
      for (int nf = 0; nf < 4; ++nf)
#pragma unroll
        for (int r = 0; r < 4; ++r) {
          float pv = exp2f(sv[nf][r] - m_run);
          sv[nf][r] = pv;
          rsum += pv;
        }
      rsum += __shfl_xor(rsum, 16, 64);
      rsum += __shfl_xor(rsum, 32, 64);
      l_run += rsum;

#pragma unroll
      for (int nf = 0; nf < 4; ++nf) {
        v2u pw;
        pw[0] = pk2(sv[nf][0], sv[nf][1]);
        pw[1] = pk2(sv[nf][2], sv[nf][3]);
        *(v2u*)(prow + ((nf * 8 + lh * 2) ^ xr)) = pw;
      }
      asm volatile("s_waitcnt lgkmcnt(0)" ::: "memory");
      __builtin_amdgcn_sched_barrier(0);  // rule 18
      v8s ap[2];
#pragma unroll
      for (int c2 = 0; c2 < 2; ++c2) ap[c2] = *(const v8s*)(prow + ((c2 * 16 + lh * 4) ^ xr));

      __builtin_amdgcn_s_setprio(1);
#pragma unroll
      for (int df = 0; df < 8; ++df)
#pragma unroll
        for (int c2 = 0; c2 < 2; ++c2)
          o_acc[df] = __builtin_amdgcn_mfma_f32_16x16x32_bf16(ap[c2], vf[df][c2], o_acc[df], 0, 0, 0);
      __builtin_amdgcn_s_setprio(0);

      __syncthreads();
      buf ^= 1;
    }

    if (fin) {
      float rl = 1.0f / l_run;
      float invq[4];
#pragma unroll
      for (int r = 0; r < 4; ++r) invq[r] = __shfl(rl, lh * 4 + r, 16);
      u16* op = O + (size_t)(b * S + q0 + w * 16 + lh * 4) * (size_t)(H * 128) + h * 128;
#pragma unroll
      for (int r = 0; r < 4; ++r)
#pragma unroll
        for (int df = 0; df < 8; ++df)
          op[(size_t)r * (H * 128) + df * 16 + lr] = f2bf(o_acc[df][r] * invq[r]);
    } else {
      const size_t idx = ((size_t)(pidx * 32 + bh) * 16 + (qt - 16));
      u16* op = o_part + idx * 8192 + (size_t)(w * 16 + lh * 4) * 128;
#pragma unroll
      for (int r = 0; r < 4; ++r)
#pragma unroll
        for (int df = 0; df < 8; ++df)
          op[(size_t)r * 128 + df * 16 + lr] = f2bf(o_acc[df][r]);
      if (lh == 0) {
        size_t mi = idx * 64 + (w * 16 + lr);
        m_part[mi] = m_run;
        l_part[mi] = l_run;
      }
    }
  }
}

// ---------------- merge the two partials of each long q-tile ----------------
__global__ __launch_bounds__(256) void k_merge(const u16* __restrict__ o_part,
                                               const float* __restrict__ m_part,
                                               const float* __restrict__ l_part,
                                               u16* __restrict__ ao, int S, int H) {
  const int bh = blockIdx.x;  // 32
  const int j = blockIdx.y;   // 16
  const int h = bh % H, b = bh / H;
  const int q0 = (16 + j) * 64;
  const int tid = threadIdx.x;
  const size_t i0 = (size_t)bh * 16 + j;
  const size_t i1 = (size_t)(32 + bh) * 16 + j;
#pragma unroll
  for (int i = 0; i < 4; ++i) {
    int c = i * 256 + tid;  // 0..1023
    int row = c >> 4, c8 = c & 15;
    float m0 = m_part[i0 * 64 + row], m1 = m_part[i1 * 64 + row];
    float l0 = l_part[i0 * 64 + row], l1 = l_part[i1 * 64 + row];
    float m = fmaxf(m0, m1);
    float a0 = exp2f(m0 - m), a1 = exp2f(m1 - m);
    float inv = 1.0f / (l0 * a0 + l1 * a1);
    a0 *= inv; a1 *= inv;
    v8s x0 = *(const v8s*)(o_part + i0 * 8192 + row * 128 + c8 * 8);
    v8s x1 = *(const v8s*)(o_part + i1 * 8192 + row * 128 + c8 * 8);
    v8s res;
#pragma unroll
    for (int e = 0; e < 8; ++e)
      res[e] = (short)f2bf(bf2f((u16)x0[e]) * a0 + bf2f((u16)x1[e]) * a1);
    *(v8s*)(ao + (size_t)(b * S + q0 + row) * (size_t)(H * 128) + h * 128 + c8 * 8) = res;
  }
}

extern "C" void kernel_launch(void* const* d_in, const int* in_sizes, int n_in, void* d_out,
                              int out_size, void* d_ws, size_t ws_size, hipStream_t stream) {
  const float* x = (const float*)d_in[0];
  const float* Wq = (const float*)d_in[1];
  const float* Wk = (const float*)d_in[2];
  const float* Wv = (const float*)d_in[3];
  const float* Wp = (const float*)d_in[4];
  const float* gain = (const float*)d_in[5];
  float* out = (float*)d_out;

  const int B = 2, S = 2048, D = 2048, H = 16, KH = 4;
  const int M = B * S;
  const int KVD = KH * 128;
  const int NQKV = D + 2 * KVD;  // 3072

  char* w = (char*)d_ws;
  u16* x_bf = (u16*)w;   w += (size_t)M * D * 2;
  u16* wqkv = (u16*)w;   w += (size_t)NQKV * D * 2;
  u16* wp_bf = (u16*)w;  w += (size_t)D * D * 2;
  u16* q_bf = (u16*)w;   w += (size_t)M * D * 2;
  u16* k_bf = (u16*)w;   w += (size_t)M * KVD * 2;
  u16* v_t = (u16*)w;    w += (size_t)M * KVD * 2;
  u16* ao_bf = (u16*)w;  w += (size_t)M * D * 2;
  float* cosT = (float*)w; w += (size_t)S * 64 * 4;
  float* sinT = (float*)w; w += (size_t)S * 64 * 4;
  if ((size_t)(w - (char*)d_ws) > ws_size) return;
  // attention partials alias regions dead after the QKV GEMM:
  u16* o_part = x_bf;                  // 2*32*16*8192 u16 = 16.78 MB
  float* m_part = (float*)wqkv;        // 256 KB
  float* l_part = m_part + 2 * 32 * 16 * 64;  // 256 KB

  k_cast_bf16<<<(M * D / 4 + 255) / 256, 256, 0, stream>>>(x, x_bf, M * D / 4);
  {
    int na4 = D * D / 4, nb4 = KVD * D / 4, nc4 = KVD * D / 4, nd4 = D * D / 4;
    int tot = na4 + nb4 + nc4 + nd4;
    k_cast_w<<<(tot + 255) / 256, 256, 0, stream>>>(
        Wq, Wk, Wv, Wp, wqkv, wqkv + (size_t)D * D, wqkv + (size_t)(D + KVD) * D, wp_bf,
        na4, nb4, nc4, nd4);
  }

  double scale = (double)S / 1024.0;
  double base = (S > 1024) ? 10000.0 * pow(scale, 128.0 / 126.0) : 10000.0;
  float l2b = (float)(log(base) / log(2.0));
  k_rope_tab<<<S * 64 / 256, 256, 0, stream>>>(cosT, sinT, l2b);

  dim3 blk(256);
  dim3 gqkv(NQKV / 128, M / 128);  // 24 x 32 = 768 blocks
  k_gemm_qkv<<<gqkv, blk, 0, stream>>>(x_bf, wqkv, q_bf, k_bf, v_t, M, D);

  float qscale = 1.4426950408889634f / sqrtf(128.0f);
  k_rmsnorm_rope<<<(M * H) / 4, 256, 0, stream>>>(q_bf, cosT, sinT, gain, H, S, qscale);
  k_rmsnorm_rope<<<(M * KH) / 4, 256, 0, stream>>>(k_bf, cosT, sinT, nullptr, KH, S, 1.0f);

  dim3 ga(B * H, 32);  // 1024 balanced blocks (16-17 tile-units each)
  k_flash_attn<<<ga, blk, 0, stream>>>(q_bf, k_bf, v_t, ao_bf, o_part, m_part, l_part,
                                       S, H, KH, M);
  dim3 gm(B * H, 16);
  k_merge<<<gm, blk, 0, stream>>>(o_part, m_part, l_part, ao_bf, S, H);

  dim3 gp(D / 128, M / 128);
  k_gemm_bt<<<gp, blk, 0, stream>>>(ao_bf, wp_bf, out, M, D, D);
}

// Round 8
// 314.618 us; speedup vs baseline: 1.5302x; 1.1742x over previous
//
#include <hip/hip_runtime.h>
#include <cmath>

typedef unsigned short u16;
typedef short v8s __attribute__((ext_vector_type(8)));
typedef float v4f __attribute__((ext_vector_type(4)));
typedef unsigned short v4u __attribute__((ext_vector_type(4)));
typedef unsigned int v2u __attribute__((ext_vector_type(2)));

__device__ __forceinline__ u16 f2bf(float f) {
  unsigned u = __builtin_bit_cast(unsigned, f);
  u += 0x7fffu + ((u >> 16) & 1u);
  return (u16)(u >> 16);
}
__device__ __forceinline__ float bf2f(u16 h) {
  unsigned u = ((unsigned)h) << 16;
  return __builtin_bit_cast(float, u);
}
__device__ __forceinline__ unsigned pk2(float a, float b) {
  return (unsigned)f2bf(a) | ((unsigned)f2bf(b) << 16);
}

// ---------------- cast fp32 -> bf16 (vectorized, G13) ----------------
__global__ void k_cast_bf16(const float* __restrict__ in, u16* __restrict__ out, int n4) {
  int i = blockIdx.x * blockDim.x + threadIdx.x;
  if (i >= n4) return;
  v4f v = ((const v4f*)in)[i];
  v4u o;
  o[0] = f2bf(v[0]); o[1] = f2bf(v[1]); o[2] = f2bf(v[2]); o[3] = f2bf(v[3]);
  ((v4u*)out)[i] = o;
}

// ---------------- fused cast of the 4 weight tensors ----------------
__global__ void k_cast_w(const float* __restrict__ a, const float* __restrict__ b,
                         const float* __restrict__ c, const float* __restrict__ d,
                         u16* __restrict__ oa, u16* __restrict__ ob, u16* __restrict__ oc,
                         u16* __restrict__ od, int na4, int nb4, int nc4, int nd4) {
  int j = blockIdx.x * blockDim.x + threadIdx.x;
  const float* src;
  u16* dst;
  if (j < na4) { src = a; dst = oa; }
  else {
    j -= na4;
    if (j < nb4) { src = b; dst = ob; }
    else {
      j -= nb4;
      if (j < nc4) { src = c; dst = oc; }
      else {
        j -= nc4;
        if (j >= nd4) return;
        src = d; dst = od;
      }
    }
  }
  v4f v = ((const v4f*)src)[j];
  v4u o;
  o[0] = f2bf(v[0]); o[1] = f2bf(v[1]); o[2] = f2bf(v[2]); o[3] = f2bf(v[3]);
  ((v4u*)dst)[j] = o;
}

// ---------------- RoPE cos/sin table [S][64] f32 ----------------
__global__ void k_rope_tab(float* __restrict__ cosT, float* __restrict__ sinT, float log2_base) {
  int idx = blockIdx.x * blockDim.x + threadIdx.x;
  int t = idx >> 6, i = idx & 63;
  float inv = exp2f(-(float)i * (1.0f / 64.0f) * log2_base);
  float fr = (float)t * inv;
  cosT[idx] = cosf(fr);
  sinT[idx] = sinf(fr);
}

// ------ per-head RMSNorm + RoPE + gain + output scale (in-place, bf16) -------
__global__ void k_rmsnorm_rope(u16* __restrict__ qk, const float* __restrict__ cosT,
                               const float* __restrict__ sinT, const float* __restrict__ gain,
                               int H, int S, float oscale) {
  int row = blockIdx.x * 4 + (threadIdx.x >> 6);
  int l = threadIdx.x & 63;
  int h = row % H;
  int m = row / H;
  int s = m % S;
  u16* p = qk + (size_t)row * 128;
  float a = bf2f(p[l]), b = bf2f(p[64 + l]);
  float ss = a * a + b * b;
#pragma unroll
  for (int o = 32; o; o >>= 1) ss += __shfl_xor(ss, o, 64);
  float r = rsqrtf(ss * (1.0f / 128.0f) + 1.1920929e-7f);
  a *= r; b *= r;
  float c = cosT[s * 64 + l], sn = sinT[s * 64 + l];
  float o1 = a * c + b * sn;
  float o2 = b * c - a * sn;
  float g = oscale;
  if (gain != nullptr) g *= gain[h];
  p[l] = f2bf(o1 * g);
  p[64 + l] = f2bf(o2 * g);
}

// -------- fused QKV GEMM: [M,2048]x[3072,2048]^T -> q/k/v_t (m97 + T1) -------
__global__ __launch_bounds__(256) void k_gemm_qkv(const u16* __restrict__ A,
                                                  const u16* __restrict__ Bw,
                                                  u16* __restrict__ q_o, u16* __restrict__ k_o,
                                                  u16* __restrict__ v_o, int M, int K) {
  __shared__ u16 sA[128 * 32];
  __shared__ u16 sB[128 * 32];
  const int tid = threadIdx.x;
  const int w = tid >> 6, l = tid & 63;
  const int lr = l & 15, lh = l >> 4;
  const int wr = w >> 1, wc = w & 1;
  const int nwg = gridDim.x * gridDim.y;
  const int bid = blockIdx.y * gridDim.x + blockIdx.x;
  const int cpx = nwg >> 3;
  const int swz = (bid & 7) * cpx + (bid >> 3);
  const int row0 = (swz / gridDim.x) * 128, col0 = (swz % gridDim.x) * 128;
  v4f zz = {0.f, 0.f, 0.f, 0.f};
  v4f acc[4][4];
#pragma unroll
  for (int mi = 0; mi < 4; ++mi)
#pragma unroll
    for (int ni = 0; ni < 4; ++ni) acc[mi][ni] = zz;

  const int lrow = l >> 2;
  const int lcol = (l & 3) * 8;

  for (int k0 = 0; k0 < K; k0 += 32) {
#pragma unroll
    for (int i = 0; i < 2; ++i) {
      int c = i * 4 + w;
      const u16* srcA = A + (size_t)(row0 + c * 16 + lrow) * K + (k0 + lcol);
      const u16* srcB = Bw + (size_t)(col0 + c * 16 + lrow) * K + (k0 + lcol);
      __builtin_amdgcn_global_load_lds((const __attribute__((address_space(1))) void*)srcA,
                                       (__attribute__((address_space(3))) void*)(sA + c * 512),
                                       16, 0, 0);
      __builtin_amdgcn_global_load_lds((const __attribute__((address_space(1))) void*)srcB,
                                       (__attribute__((address_space(3))) void*)(sB + c * 512),
                                       16, 0, 0);
    }
    __syncthreads();
    v8s af[4], bfr[4];
#pragma unroll
    for (int mi = 0; mi < 4; ++mi)
      af[mi] = *(const v8s*)(sA + (wr * 64 + mi * 16 + lr) * 32 + lh * 8);
#pragma unroll
    for (int ni = 0; ni < 4; ++ni)
      bfr[ni] = *(const v8s*)(sB + (wc * 64 + ni * 16 + lr) * 32 + lh * 8);
#pragma unroll
    for (int mi = 0; mi < 4; ++mi)
#pragma unroll
      for (int ni = 0; ni < 4; ++ni)
        acc[mi][ni] = __builtin_amdgcn_mfma_f32_16x16x32_bf16(af[mi], bfr[ni], acc[mi][ni], 0, 0, 0);
    __syncthreads();
  }
  u16* outp;
  int ldo = 0, cb;
  bool tr = false;
  if (col0 < 2048) { outp = q_o; ldo = 2048; cb = col0; }
  else if (col0 < 2560) { outp = k_o; ldo = 512; cb = col0 - 2048; }
  else { outp = v_o; tr = true; cb = col0 - 2560; }
#pragma unroll
  for (int mi = 0; mi < 4; ++mi) {
#pragma unroll
    for (int ni = 0; ni < 4; ++ni) {
      int row = row0 + wr * 64 + mi * 16 + lh * 4;
      int col = cb + wc * 64 + ni * 16 + lr;
#pragma unroll
      for (int r = 0; r < 4; ++r) {
        u16 bv = f2bf(acc[mi][ni][r]);
        if (tr) outp[(size_t)col * M + row + r] = bv;
        else    outp[(size_t)(row + r) * ldo + col] = bv;
      }
    }
  }
}

// ---------------- out-proj GEMM: C[M,N] = A[M,K] * Bw[N,K]^T (m97 + T1) ------
__global__ __launch_bounds__(256) void k_gemm_bt(const u16* __restrict__ A,
                                                 const u16* __restrict__ Bw,
                                                 float* __restrict__ C, int M, int N, int K) {
  __shared__ u16 sA[128 * 32];
  __shared__ u16 sB[128 * 32];
  const int tid = threadIdx.x;
  const int w = tid >> 6, l = tid & 63;
  const int lr = l & 15, lh = l >> 4;
  const int wr = w >> 1, wc = w & 1;
  const int nwg = gridDim.x * gridDim.y;
  const int bid = blockIdx.y * gridDim.x + blockIdx.x;
  const int cpx = nwg >> 3;
  const int swz = (bid & 7) * cpx + (bid >> 3);
  const int row0 = (swz / gridDim.x) * 128, col0 = (swz % gridDim.x) * 128;
  v4f zz = {0.f, 0.f, 0.f, 0.f};
  v4f acc[4][4];
#pragma unroll
  for (int mi = 0; mi < 4; ++mi)
#pragma unroll
    for (int ni = 0; ni < 4; ++ni) acc[mi][ni] = zz;

  const int lrow = l >> 2;
  const int lcol = (l & 3) * 8;

  for (int k0 = 0; k0 < K; k0 += 32) {
#pragma unroll
    for (int i = 0; i < 2; ++i) {
      int c = i * 4 + w;
      const u16* srcA = A + (size_t)(row0 + c * 16 + lrow) * K + (k0 + lcol);
      const u16* srcB = Bw + (size_t)(col0 + c * 16 + lrow) * K + (k0 + lcol);
      __builtin_amdgcn_global_load_lds((const __attribute__((address_space(1))) void*)srcA,
                                       (__attribute__((address_space(3))) void*)(sA + c * 512),
                                       16, 0, 0);
      __builtin_amdgcn_global_load_lds((const __attribute__((address_space(1))) void*)srcB,
                                       (__attribute__((address_space(3))) void*)(sB + c * 512),
                                       16, 0, 0);
    }
    __syncthreads();
    v8s af[4], bfr[4];
#pragma unroll
    for (int mi = 0; mi < 4; ++mi)
      af[mi] = *(const v8s*)(sA + (wr * 64 + mi * 16 + lr) * 32 + lh * 8);
#pragma unroll
    for (int ni = 0; ni < 4; ++ni)
      bfr[ni] = *(const v8s*)(sB + (wc * 64 + ni * 16 + lr) * 32 + lh * 8);
#pragma unroll
    for (int mi = 0; mi < 4; ++mi)
#pragma unroll
      for (int ni = 0; ni < 4; ++ni)
        acc[mi][ni] = __builtin_amdgcn_mfma_f32_16x16x32_bf16(af[mi], bfr[ni], acc[mi][ni], 0, 0, 0);
    __syncthreads();
  }
#pragma unroll
  for (int mi = 0; mi < 4; ++mi) {
#pragma unroll
    for (int ni = 0; ni < 4; ++ni) {
      int row = row0 + wr * 64 + mi * 16 + lh * 4;
      int col = col0 + wc * 64 + ni * 16 + lr;
#pragma unroll
      for (int r = 0; r < 4; ++r) C[(size_t)(row + r) * N + col] = acc[mi][ni][r];
    }
  }
}

// ---------------- causal GQA flash attention v8 (balanced split, low-VGPR) ---
// grid (B*H, 32), balanced 16-17 tile-units per block (KV-split + merge).
// V prefetch halved to 32 VGPRs via two-chunk PV with register REUSE
// (sched_barrier stops the compiler hoisting chunk-B loads over chunk-A MFMAs)
// -> target VGPR <= 128 so all 4 work-blocks/CU are co-resident (16 waves/CU).
__global__ __launch_bounds__(256) void k_flash_attn(
    const u16* __restrict__ Q, const u16* __restrict__ Kb, const u16* __restrict__ Vt,
    u16* __restrict__ O, u16* __restrict__ o_part, float* __restrict__ m_part,
    float* __restrict__ l_part, int S, int H, int KH, int Mtot) {
  const int bh = blockIdx.x;
  const int slot = blockIdx.y;
  const int h = bh % H, b = bh / H;
  const int kvh = h / (H / KH);
  const int w = threadIdx.x >> 6, l = threadIdx.x & 63;
  const int lr = l & 15, lh = l >> 4;

  __shared__ alignas(16) char sK[2][16384];           // 64 kv-rows x 256B, swizzled
  __shared__ alignas(16) unsigned P_lds[4][16 * 32];  // per-wave packed P, XOR-swizzled
  unsigned* prow = P_lds[w] + lr * 32;
  const int xr = (lr & 7) << 2;

  v4f zz = {0.f, 0.f, 0.f, 0.f};
  const int strideK = KH * 128;
  const int strideKB = strideK * 2;
  const char* KheadB = (const char*)Kb + 2 * ((size_t)b * S * strideK + (size_t)kvh * 128);
  const u16* Vbase = Vt + (size_t)(kvh * 128) * Mtot + (size_t)b * S;

  const int nseg = (slot < 16) ? 1 : 2;
  for (int seg = 0; seg < nseg; ++seg) {
    int qt, t0, t1, pidx;
    bool fin;
    if (slot < 16) {
      qt = 16 + slot; t0 = 0; t1 = 16; fin = false; pidx = 0;
    } else {
      const int s = slot - 16;
      if (seg == 0) { qt = 16 + s; t0 = 16; t1 = 17 + s; fin = false; pidx = 1; }
      else          { qt = 15 - s; t0 = 0;  t1 = 16 - s; fin = true;  pidx = 0; }
    }
    const int q0 = qt * 64;
    const int qi = q0 + w * 16 + lr;

    v8s qf[4];
    const u16* qp = Q + (size_t)(b * S + q0 + w * 16 + lr) * (size_t)(H * 128) + h * 128 + lh * 8;
#pragma unroll
    for (int c = 0; c < 4; ++c) qf[c] = *(const v8s*)(qp + c * 32);

    v4f o_acc[8];
#pragma unroll
    for (int df = 0; df < 8; ++df) o_acc[df] = zz;
    float m_run = -1e30f, l_run = 0.f;

    // prologue: stage tile t0 into buf 0
    {
      const char* Kt = KheadB + (size_t)(t0 * 64) * strideKB;
#pragma unroll
      for (int j = 0; j < 4; ++j) {
        int jj = w * 4 + j;
        int ci = jj * 64 + l;
        int r = ci >> 4;
        int bc = (ci & 15) << 4;
        const char* src = Kt + (size_t)r * strideKB + (bc ^ ((r & 15) << 4));
        __builtin_amdgcn_global_load_lds((const __attribute__((address_space(1))) void*)src,
                                         (__attribute__((address_space(3))) void*)(sK[0] + jj * 1024),
                                         16, 0, 0);
      }
    }
    __syncthreads();

    int buf = 0;
    for (int t = t0; t < t1; ++t) {
      const int kv0 = t * 64;
      const bool lastTile = (t == t1 - 1);
      const char* sKb = sK[buf];

      v4f sv[4];
      __builtin_amdgcn_s_setprio(1);
#pragma unroll
      for (int nf = 0; nf < 4; ++nf) {
        v4f a_ = zz;
        const int r = nf * 16 + lr;
#pragma unroll
        for (int c = 0; c < 4; ++c) {
          v8s kf = *(const v8s*)(sKb + r * 256 + ((lh * 16 + c * 64) ^ (lr << 4)));
          a_ = __builtin_amdgcn_mfma_f32_16x16x32_bf16(kf, qf[c], a_, 0, 0, 0);
        }
        sv[nf] = a_;
      }
      __builtin_amdgcn_s_setprio(0);

      // ---- prefetch V chunk A (df 0..3) only: 32 VGPRs ----
      v8s vf[4][2];
#pragma unroll
      for (int df = 0; df < 4; ++df) {
        const u16* vp = Vbase + (size_t)(df * 16 + lr) * Mtot + kv0 + lh * 8;
#pragma unroll
        for (int c2 = 0; c2 < 2; ++c2) vf[df][c2] = *(const v8s*)(vp + c2 * 32);
      }

      // ---- stage next K tile ----
      if (t + 1 < t1) {
        const char* Kt = KheadB + (size_t)(kv0 + 64) * strideKB;
        char* dst = (char*)sK[buf ^ 1];
#pragma unroll
        for (int j = 0; j < 4; ++j) {
          int jj = w * 4 + j;
          int ci = jj * 64 + l;
          int r = ci >> 4;
          int bc = (ci & 15) << 4;
          const char* src = Kt + (size_t)r * strideKB + (bc ^ ((r & 15) << 4));
          __builtin_amdgcn_global_load_lds((const __attribute__((address_space(1))) void*)src,
                                           (__attribute__((address_space(3))) void*)(dst + jj * 1024),
                                           16, 0, 0);
        }
      }

      if (lastTile) {  // no-op for head pieces (kv always <= qi there)
#pragma unroll
        for (int nf = 0; nf < 4; ++nf)
#pragma unroll
          for (int r = 0; r < 4; ++r)
            if (kv0 + nf * 16 + lh * 4 + r > qi) sv[nf][r] = -1e30f;
      }
      float pmax = -1e30f;
#pragma unroll
      for (int nf = 0; nf < 4; ++nf)
#pragma unroll
        for (int r = 0; r < 4; ++r) pmax = fmaxf(pmax, sv[nf][r]);
      pmax = fmaxf(pmax, __shfl_xor(pmax, 16, 64));
      pmax = fmaxf(pmax, __shfl_xor(pmax, 32, 64));
      if (!__all(pmax - m_run <= 8.0f)) {  // T13 defer-max
        float mnew = fmaxf(m_run, pmax);
        float corr = exp2f(m_run - mnew);
        l_run *= corr;
        m_run = mnew;
        float corrq[4];
#pragma unroll
        for (int r = 0; r < 4; ++r) corrq[r] = __shfl(corr, lh * 4 + r, 16);
#pragma unroll
        for (int df = 0; df < 8; ++df)
#pragma unroll
          for (int r = 0; r < 4; ++r) o_acc[df][r] *= corrq[r];
      }
      float rsum = 0.f;
#pragma unroll
      for (int nf = 0; nf < 4; ++nf)
#pragma unroll
        for (int r = 0; r < 4; ++r) {
          float pv = exp2f(sv[nf][r] - m_run);
          sv[nf][r] = pv;
          rsum += pv;
        }
      rsum += __shfl_xor(rsum, 16, 64);
      rsum += __shfl_xor(rsum, 32, 64);
      l_run += rsum;

#pragma unroll
      for (int nf = 0; nf < 4; ++nf) {
        v2u pw;
        pw[0] = pk2(sv[nf][0], sv[nf][1]);
        pw[1] = pk2(sv[nf][2], sv[nf][3]);
        *(v2u*)(prow + ((nf * 8 + lh * 2) ^ xr)) = pw;
      }
      asm volatile("s_waitcnt lgkmcnt(0)" ::: "memory");
      __builtin_amdgcn_sched_barrier(0);  // rule 18
      v8s ap[2];
#pragma unroll
      for (int c2 = 0; c2 < 2; ++c2) ap[c2] = *(const v8s*)(prow + ((c2 * 16 + lh * 4) ^ xr));

      // ---- PV chunk A (df 0..3) ----
      __builtin_amdgcn_s_setprio(1);
#pragma unroll
      for (int df = 0; df < 4; ++df)
#pragma unroll
        for (int c2 = 0; c2 < 2; ++c2)
          o_acc[df] = __builtin_amdgcn_mfma_f32_16x16x32_bf16(ap[c2], vf[df][c2], o_acc[df], 0, 0, 0);
      __builtin_amdgcn_s_setprio(0);
      __builtin_amdgcn_sched_barrier(0);  // keep chunk-B loads BELOW chunk-A MFMAs (reg reuse)

      // ---- reload vf with chunk B (df 4..7), then PV chunk B ----
#pragma unroll
      for (int df = 0; df < 4; ++df) {
        const u16* vp = Vbase + (size_t)((df + 4) * 16 + lr) * Mtot + kv0 + lh * 8;
#pragma unroll
        for (int c2 = 0; c2 < 2; ++c2) vf[df][c2] = *(const v8s*)(vp + c2 * 32);
      }
      __builtin_amdgcn_s_setprio(1);
#pragma unroll
      for (int df = 0; df < 4; ++df)
#pragma unroll
        for (int c2 = 0; c2 < 2; ++c2)
          o_acc[df + 4] =
              __builtin_amdgcn_mfma_f32_16x16x32_bf16(ap[c2], vf[df][c2], o_acc[df + 4], 0, 0, 0);
      __builtin_amdgcn_s_setprio(0);

      __syncthreads();
      buf ^= 1;
    }

    if (fin) {
      float rl = 1.0f / l_run;
      float invq[4];
#pragma unroll
      for (int r = 0; r < 4; ++r) invq[r] = __shfl(rl, lh * 4 + r, 16);
      u16* op = O + (size_t)(b * S + q0 + w * 16 + lh * 4) * (size_t)(H * 128) + h * 128;
#pragma unroll
      for (int r = 0; r < 4; ++r)
#pragma unroll
        for (int df = 0; df < 8; ++df)
          op[(size_t)r * (H * 128) + df * 16 + lr] = f2bf(o_acc[df][r] * invq[r]);
    } else {
      const size_t idx = ((size_t)(pidx * 32 + bh) * 16 + (qt - 16));
      u16* op = o_part + idx * 8192 + (size_t)(w * 16 + lh * 4) * 128;
#pragma unroll
      for (int r = 0; r < 4; ++r)
#pragma unroll
        for (int df = 0; df < 8; ++df)
          op[(size_t)r * 128 + df * 16 + lr] = f2bf(o_acc[df][r]);
      if (lh == 0) {
        size_t mi = idx * 64 + (w * 16 + lr);
        m_part[mi] = m_run;
        l_part[mi] = l_run;
      }
    }
  }
}

// ---------------- merge the two partials of each long q-tile ----------------
__global__ __launch_bounds__(256) void k_merge(const u16* __restrict__ o_part,
                                               const float* __restrict__ m_part,
                                               const float* __restrict__ l_part,
                                               u16* __restrict__ ao, int S, int H) {
  const int bh = blockIdx.x;  // 32
  const int j = blockIdx.y;   // 16
  const int h = bh % H, b = bh / H;
  const int q0 = (16 + j) * 64;
  const int tid = threadIdx.x;
  const size_t i0 = (size_t)bh * 16 + j;
  const size_t i1 = (size_t)(32 + bh) * 16 + j;
#pragma unroll
  for (int i = 0; i < 4; ++i) {
    int c = i * 256 + tid;  // 0..1023
    int row = c >> 4, c8 = c & 15;
    float m0 = m_part[i0 * 64 + row], m1 = m_part[i1 * 64 + row];
    float l0 = l_part[i0 * 64 + row], l1 = l_part[i1 * 64 + row];
    float m = fmaxf(m0, m1);
    float a0 = exp2f(m0 - m), a1 = exp2f(m1 - m);
    float inv = 1.0f / (l0 * a0 + l1 * a1);
    a0 *= inv; a1 *= inv;
    v8s x0 = *(const v8s*)(o_part + i0 * 8192 + row * 128 + c8 * 8);
    v8s x1 = *(const v8s*)(o_part + i1 * 8192 + row * 128 + c8 * 8);
    v8s res;
#pragma unroll
    for (int e = 0; e < 8; ++e)
      res[e] = (short)f2bf(bf2f((u16)x0[e]) * a0 + bf2f((u16)x1[e]) * a1);
    *(v8s*)(ao + (size_t)(b * S + q0 + row) * (size_t)(H * 128) + h * 128 + c8 * 8) = res;
  }
}

extern "C" void kernel_launch(void* const* d_in, const int* in_sizes, int n_in, void* d_out,
                              int out_size, void* d_ws, size_t ws_size, hipStream_t stream) {
  const float* x = (const float*)d_in[0];
  const float* Wq = (const float*)d_in[1];
  const float* Wk = (const float*)d_in[2];
  const float* Wv = (const float*)d_in[3];
  const float* Wp = (const float*)d_in[4];
  const float* gain = (const float*)d_in[5];
  float* out = (float*)d_out;

  const int B = 2, S = 2048, D = 2048, H = 16, KH = 4;
  const int M = B * S;
  const int KVD = KH * 128;
  const int NQKV = D + 2 * KVD;  // 3072

  char* w = (char*)d_ws;
  u16* x_bf = (u16*)w;   w += (size_t)M * D * 2;
  u16* wqkv = (u16*)w;   w += (size_t)NQKV * D * 2;
  u16* wp_bf = (u16*)w;  w += (size_t)D * D * 2;
  u16* q_bf = (u16*)w;   w += (size_t)M * D * 2;
  u16* k_bf = (u16*)w;   w += (size_t)M * KVD * 2;
  u16* v_t = (u16*)w;    w += (size_t)M * KVD * 2;
  u16* ao_bf = (u16*)w;  w += (size_t)M * D * 2;
  float* cosT = (float*)w; w += (size_t)S * 64 * 4;
  float* sinT = (float*)w; w += (size_t)S * 64 * 4;
  if ((size_t)(w - (char*)d_ws) > ws_size) return;
  // attention partials alias regions dead after the QKV GEMM:
  u16* o_part = x_bf;                  // 2*32*16*8192 u16 = 16.78 MB
  float* m_part = (float*)wqkv;        // 256 KB
  float* l_part = m_part + 2 * 32 * 16 * 64;  // 256 KB

  k_cast_bf16<<<(M * D / 4 + 255) / 256, 256, 0, stream>>>(x, x_bf, M * D / 4);
  {
    int na4 = D * D / 4, nb4 = KVD * D / 4, nc4 = KVD * D / 4, nd4 = D * D / 4;
    int tot = na4 + nb4 + nc4 + nd4;
    k_cast_w<<<(tot + 255) / 256, 256, 0, stream>>>(
        Wq, Wk, Wv, Wp, wqkv, wqkv + (size_t)D * D, wqkv + (size_t)(D + KVD) * D, wp_bf,
        na4, nb4, nc4, nd4);
  }

  double scale = (double)S / 1024.0;
  double base = (S > 1024) ? 10000.0 * pow(scale, 128.0 / 126.0) : 10000.0;
  float l2b = (float)(log(base) / log(2.0));
  k_rope_tab<<<S * 64 / 256, 256, 0, stream>>>(cosT, sinT, l2b);

  dim3 blk(256);
  dim3 gqkv(NQKV / 128, M / 128);  // 24 x 32 = 768 blocks
  k_gemm_qkv<<<gqkv, blk, 0, stream>>>(x_bf, wqkv, q_bf, k_bf, v_t, M, D);

  float qscale = 1.4426950408889634f / sqrtf(128.0f);
  k_rmsnorm_rope<<<(M * H) / 4, 256, 0, stream>>>(q_bf, cosT, sinT, gain, H, S, qscale);
  k_rmsnorm_rope<<<(M * KH) / 4, 256, 0, stream>>>(k_bf, cosT, sinT, nullptr, KH, S, 1.0f);

  dim3 ga(B * H, 32);  // 1024 balanced blocks (16-17 tile-units each)
  k_flash_attn<<<ga, blk, 0, stream>>>(q_bf, k_bf, v_t, ao_bf, o_part, m_part, l_part,
                                       S, H, KH, M);
  dim3 gm(B * H, 16);
  k_merge<<<gm, blk, 0, stream>>>(o_part, m_part, l_part, ao_bf, S, H);

  dim3 gp(D / 128, M / 128);
  k_gemm_bt<<<gp, blk, 0, stream>>>(ao_bf, wp_bf, out, M, D, D);
}